// Round 2
// baseline (70.439 us; speedup 1.0000x reference)
//
#include <hip/hip_runtime.h>
#include <math.h>

// MVAE forward, persistent kernel.
// Key idea: ALL weights a wave needs (~110 floats/lane) are preloaded into
// registers at kernel start (no dependence on activations), so the 8 grid
// barriers gate only tiny activation vectors. Barrier = per-WG flag on its
// own cacheline (parallel arrival stores) + wave-0 parallel poll.

#define NWG   64
#define BLOCK 256

__device__ int   g_flag[1024];          // flag[b*16], one cacheline per WG
__device__ float g_a0[256], g_a1[256], g_a2[256];
__device__ float g_mu[64], g_lv[64], g_z[64];
__device__ float g_g0[256], g_g1[256], g_g2[256];
__device__ float g_gates[16];
__device__ float g_h0[1536], g_h1[1536], g_h2[1536];
__device__ float g_oute[384];

struct P {
  const float *prev, *curr, *eps;
  const float *ew0,*eb0,*ew1,*eb1,*ew2,*eb2;
  const float *muw,*mub,*lvw,*lvb;
  const float *gw0,*gb0,*gw1,*gb1,*gw2,*gb2,*gw3,*gb3;
  const float *xw0,*xb0,*xw1,*xb1,*xw2,*xb2,*xw3,*xb3;
  float* out;
};

__device__ __forceinline__ float wred(float v) {
#pragma unroll
  for (int m = 32; m; m >>= 1) v += __shfl_xor(v, m, 64);
  return v;
}

__device__ __forceinline__ float elu(float x) { return x > 0.f ? x : expm1f(x); }

__device__ __forceinline__ float dot4(float4 a, float4 b) {
  return a.x*b.x + a.y*b.y + a.z*b.z + a.w*b.w;
}

// grid barrier: per-WG flag (release), wave-0 polls all 64 flags in parallel
__device__ __forceinline__ void gridbar(int phase) {
  __syncthreads();
  if (threadIdx.x == 0) {
    __threadfence();   // release: flush this WG's stores to coherence point
    __hip_atomic_store(&g_flag[blockIdx.x * 16], phase,
                       __ATOMIC_RELAXED, __HIP_MEMORY_SCOPE_AGENT);
  }
  if (threadIdx.x < 64) {  // wave 0: lane i watches WG i's flag
    while (__hip_atomic_load(&g_flag[threadIdx.x * 16],
                             __ATOMIC_RELAXED, __HIP_MEMORY_SCOPE_AGENT) < phase)
      __builtin_amdgcn_s_sleep(2);
  }
  __syncthreads();
  __threadfence();   // acquire for all threads before reading activations
}

__global__ void mvae_init() {
  for (int i = threadIdx.x; i < 1024; i += BLOCK) g_flag[i] = 0;
}

__global__ __launch_bounds__(BLOCK, 1) void mvae_main(P p) {
  const int tid  = threadIdx.x;
  const int lane = tid & 63;
  const int wv   = blockIdx.x * 4 + (tid >> 6);  // 0..255

  // ================= PRELOAD: all weights -> registers =================
  // S0: enc0 row wv, 124 floats (lanes 0..30 hold float4)
  float4 w0 = make_float4(0.f,0.f,0.f,0.f);
  if (lane < 31) w0 = *(const float4*)(p.ew0 + wv * 124 + 4 * lane);
  float b0 = p.eb0[wv];
  // S1/S2: enc1/enc2 row wv, 256 floats
  float4 w1 = *(const float4*)(p.ew1 + wv * 256 + 4 * lane);
  float b1 = p.eb1[wv];
  float4 w2 = *(const float4*)(p.ew2 + wv * 256 + 4 * lane);
  float b2 = p.eb2[wv];
  // S3: mu rows 0..31 (waves 0..31), lv rows 0..31 (waves 32..63)
  float4 w3 = make_float4(0.f,0.f,0.f,0.f); float b3 = 0.f;
  if (wv < 64) {
    const float* base = (wv < 32) ? (p.muw + wv * 256) : (p.lvw + (wv - 32) * 256);
    w3 = *(const float4*)(base + 4 * lane);
    b3 = (wv < 32) ? p.mub[wv] : p.lvb[wv - 32];
  }
  // S4: 7 rows of len 94 (k=0 gate0 row wv; k>=1 expert0 row wv+256(k-1))
  float w4a[7], w4b[7], b4[7];
#pragma unroll
  for (int k = 0; k < 7; ++k) {
    const float* wr = (k == 0) ? (p.gw0 + wv * 94)
                               : (p.xw0 + (wv + 256 * (k - 1)) * 94);
    w4a[k] = wr[lane];
    w4b[k] = (lane < 30) ? wr[64 + lane] : 0.f;
    b4[k]  = (k == 0) ? p.gb0[wv] : p.xb0[wv + 256 * (k - 1)];
  }
  // S5: k=0 gate1 row wv (256); k>=1 expert1 row wv+256(k-1) (288)
  float4 w5v[7]; float w5e[7]; float b5[7];
#pragma unroll
  for (int k = 0; k < 7; ++k) {
    if (k == 0) {
      w5v[0] = *(const float4*)(p.gw1 + wv * 256 + 4 * lane);
      w5e[0] = 0.f;  b5[0] = p.gb1[wv];
    } else {
      const float* wr = p.xw1 + (wv + 256 * (k - 1)) * 288;
      w5v[k] = *(const float4*)(wr + 4 * lane);
      w5e[k] = (lane < 32) ? wr[256 + lane] : 0.f;
      b5[k]  = p.xb1[wv + 256 * (k - 1)];
    }
  }
  // S6: same shape with gate2/expert2
  float4 w6v[7]; float w6e[7]; float b6[7];
#pragma unroll
  for (int k = 0; k < 7; ++k) {
    if (k == 0) {
      w6v[0] = *(const float4*)(p.gw2 + wv * 256 + 4 * lane);
      w6e[0] = 0.f;  b6[0] = p.gb2[wv];
    } else {
      const float* wr = p.xw2 + (wv + 256 * (k - 1)) * 288;
      w6v[k] = *(const float4*)(wr + 4 * lane);
      w6e[k] = (lane < 32) ? wr[256 + lane] : 0.f;
      b6[k]  = p.xb2[wv + 256 * (k - 1)];
    }
  }
  // S7: rowA = wv (wv<6: gate3 row; else out_e row wv-6); rowB = out_e row wv+250 (wv<122)
  float4 wAv = make_float4(0.f,0.f,0.f,0.f); float wAe = 0.f, bA = 0.f;
  if (wv < 6) {
    wAv = *(const float4*)(p.gw3 + wv * 256 + 4 * lane);
    bA  = p.gb3[wv];
  } else {
    const float* wr = p.xw3 + (wv - 6) * 288;
    wAv = *(const float4*)(wr + 4 * lane);
    wAe = (lane < 32) ? wr[256 + lane] : 0.f;
    bA  = p.xb3[wv - 6];
  }
  float4 wBv = make_float4(0.f,0.f,0.f,0.f); float wBe = 0.f, bB = 0.f;
  if (wv < 122) {
    const float* wr = p.xw3 + (wv + 250) * 288;
    wBv = *(const float4*)(wr + 4 * lane);
    wBe = (lane < 32) ? wr[256 + lane] : 0.f;
    bB  = p.xb3[wv + 250];
  }
  // small inputs
  float epsL    = (lane < 32) ? p.eps[lane] : 0.f;
  float prev_m  = (lane >= 32) ? p.prev[lane - 32] : 0.f;   // x[lane] for lane>=32 in S4
  float prev_hi = (lane < 30) ? p.prev[32 + lane] : 0.f;    // x[64+lane] in S4
  float4 x0 = make_float4(0.f,0.f,0.f,0.f);
  if (lane < 31) {
    int i0 = 4 * lane;
    x0.x = (i0 + 0 < 62) ? p.prev[i0 + 0] : p.curr[i0 + 0 - 62];
    x0.y = (i0 + 1 < 62) ? p.prev[i0 + 1] : p.curr[i0 + 1 - 62];
    x0.z = (i0 + 2 < 62) ? p.prev[i0 + 2] : p.curr[i0 + 2 - 62];
    x0.w = (i0 + 3 < 62) ? p.prev[i0 + 3] : p.curr[i0 + 3 - 62];
  }

  // ================= STAGES =================
  // S0: enc0
  {
    float s = wred(dot4(w0, x0));
    if (!lane) g_a0[wv] = elu(s + b0);
  }
  gridbar(1);

  // S1: enc1
  {
    float4 x = *(const float4*)(g_a0 + 4 * lane);
    float s = wred(dot4(w1, x));
    if (!lane) g_a1[wv] = elu(s + b1);
  }
  gridbar(2);

  // S2: enc2
  {
    float4 x = *(const float4*)(g_a1 + 4 * lane);
    float s = wred(dot4(w2, x));
    if (!lane) g_a2[wv] = elu(s + b2);
  }
  gridbar(3);

  // S3: mu / logvar (also straight to d_out)
  if (wv < 64) {
    float4 x = *(const float4*)(g_a2 + 4 * lane);
    float s = wred(dot4(w3, x));
    if (!lane) {
      float v = s + b3;
      if (wv < 32) { g_mu[wv] = v;      p.out[62 + wv] = v; }
      else         { g_lv[wv - 32] = v; p.out[94 + (wv - 32)] = v; }
    }
  }
  gridbar(4);

  // S4: gate0 + expert h0 (x = [z | prev], len 94)
  {
    float z = 0.f;
    if (lane < 32) z = g_mu[lane] + epsL * expf(0.5f * g_lv[lane]);
    if (wv == 0 && lane < 32) g_z[lane] = z;      // publish z for later stages
    float xa = (lane < 32) ? z : prev_m;
#pragma unroll
    for (int k = 0; k < 7; ++k) {
      float s = w4a[k] * xa + w4b[k] * prev_hi;
      s = wred(s);
      if (!lane) {
        if (k == 0) g_g0[wv] = elu(s + b4[0]);
        else        g_h0[wv + 256 * (k - 1)] = elu(s + b4[k]);
      }
    }
  }
  gridbar(5);

  // S5: gate1 + expert h1
  {
    float4 xz = make_float4(0.f,0.f,0.f,0.f);
    if (lane < 8) xz = *(const float4*)(g_z + 4 * lane);
#pragma unroll
    for (int k = 0; k < 7; ++k) {
      if (k == 0) {
        float4 x = *(const float4*)(g_g0 + 4 * lane);
        float s = wred(dot4(w5v[0], x));
        if (!lane) g_g1[wv] = elu(s + b5[0]);
      } else {
        const float* h = g_h0 + (k - 1) * 256;
        float4 xh;
        if (lane < 8) xh = xz;
        else          xh = *(const float4*)(h + 4 * lane - 32);
        float s = dot4(w5v[k], xh);
        if (lane < 32) s += w5e[k] * h[224 + lane];
        s = wred(s);
        if (!lane) g_h1[wv + 256 * (k - 1)] = elu(s + b5[k]);
      }
    }
  }
  gridbar(6);

  // S6: gate2 + expert h2
  {
    float4 xz = make_float4(0.f,0.f,0.f,0.f);
    if (lane < 8) xz = *(const float4*)(g_z + 4 * lane);
#pragma unroll
    for (int k = 0; k < 7; ++k) {
      if (k == 0) {
        float4 x = *(const float4*)(g_g1 + 4 * lane);
        float s = wred(dot4(w6v[0], x));
        if (!lane) g_g2[wv] = elu(s + b6[0]);
      } else {
        const float* h = g_h1 + (k - 1) * 256;
        float4 xh;
        if (lane < 8) xh = xz;
        else          xh = *(const float4*)(h + 4 * lane - 32);
        float s = dot4(w6v[k], xh);
        if (lane < 32) s += w6e[k] * h[224 + lane];
        s = wred(s);
        if (!lane) g_h2[wv + 256 * (k - 1)] = elu(s + b6[k]);
      }
    }
  }
  gridbar(7);

  // S7: gate3 logits + out_e
  {
    float4 xz = make_float4(0.f,0.f,0.f,0.f);
    if (lane < 8) xz = *(const float4*)(g_z + 4 * lane);
    if (wv < 6) {
      float4 x = *(const float4*)(g_g2 + 4 * lane);
      float s = wred(dot4(wAv, x));
      if (!lane) g_gates[wv] = s + bA;
    } else {
      int q = wv - 6; int e = q / 62;
      const float* h = g_h2 + e * 256;
      float4 xh;
      if (lane < 8) xh = xz;
      else          xh = *(const float4*)(h + 4 * lane - 32);
      float s = dot4(wAv, xh);
      if (lane < 32) s += wAe * h[224 + lane];
      s = wred(s);
      if (!lane) g_oute[q] = s + bA;
    }
    if (wv < 122) {
      int q = wv + 250; int e = q / 62;
      const float* h = g_h2 + e * 256;
      float4 xh;
      if (lane < 8) xh = xz;
      else          xh = *(const float4*)(h + 4 * lane - 32);
      float s = dot4(wBv, xh);
      if (lane < 32) s += wBe * h[224 + lane];
      s = wred(s);
      if (!lane) g_oute[q] = s + bB;
    }
  }
  gridbar(8);

  // S8: decoded = sum_e out_e * gates[e]
  if (blockIdx.x == 0 && tid < 62) {
    float s = 0.f;
#pragma unroll
    for (int e = 0; e < 6; ++e) s += g_oute[e * 62 + tid] * g_gates[e];
    p.out[tid] = s;
  }
}

extern "C" void kernel_launch(void* const* d_in, const int* in_sizes, int n_in,
                              void* d_out, int out_size, void* d_ws, size_t ws_size,
                              hipStream_t stream) {
  (void)in_sizes; (void)n_in; (void)d_ws; (void)ws_size; (void)out_size;
  const float* const* in = (const float* const*)d_in;
  P p;
  p.prev = in[0];  p.curr = in[1];  p.eps = in[2];
  p.ew0 = in[3];   p.eb0 = in[4];   p.ew1 = in[5];  p.eb1 = in[6];
  p.ew2 = in[7];   p.eb2 = in[8];
  p.muw = in[9];   p.mub = in[10];  p.lvw = in[11]; p.lvb = in[12];
  p.gw0 = in[13];  p.gb0 = in[14];  p.gw1 = in[15]; p.gb1 = in[16];
  p.gw2 = in[17];  p.gb2 = in[18];  p.gw3 = in[19]; p.gb3 = in[20];
  p.xw0 = in[21];  p.xb0 = in[22];  p.xw1 = in[23]; p.xb1 = in[24];
  p.xw2 = in[25];  p.xb2 = in[26];  p.xw3 = in[27]; p.xb3 = in[28];
  p.out = (float*)d_out;

  mvae_init<<<1, BLOCK, 0, stream>>>();
  mvae_main<<<NWG, BLOCK, 0, stream>>>(p);
}

// Round 3
// 49.908 us; speedup vs baseline: 1.4114x; 1.4114x over previous
//
#include <hip/hip_runtime.h>
#include <math.h>

// MVAE forward, persistent kernel, NO cache-invalidating fences.
// Cross-WG data (activations, flags) uses relaxed agent-scope atomics (sc1,
// coherent at MALL, bypassing non-coherent per-XCD L2). Weights use plain
// cached loads and stay L2-resident: no __threadfence anywhere.
// mu/lv/z computed redundantly per-WG (LDS) to remove one grid barrier.

#define NWG   64
#define BLOCK 256

__device__ float g_a0[256], g_a1[256], g_a2[256];
__device__ float g_g0[256], g_g1[256], g_g2[256];
__device__ float g_gates[16];
__device__ float g_h0[1536], g_h1[1536], g_h2[1536];
__device__ float g_oute[384];

struct P {
  const float *prev, *curr, *eps;
  const float *ew0,*eb0,*ew1,*eb1,*ew2,*eb2;
  const float *muw,*mub,*lvw,*lvb;
  const float *gw0,*gb0,*gw1,*gb1,*gw2,*gb2,*gw3,*gb3;
  const float *xw0,*xb0,*xw1,*xb1,*xw2,*xb2,*xw3,*xb3;
  float* out;
};

// ---- device-coherent scalar access (sc1): bypasses L1/L2, no cache inv ----
__device__ __forceinline__ float cload(const float* a) {
  int v = __hip_atomic_load((const int*)a, __ATOMIC_RELAXED,
                            __HIP_MEMORY_SCOPE_AGENT);
  return __int_as_float(v);
}
__device__ __forceinline__ void cstore(float* a, float v) {
  __hip_atomic_store((int*)a, __float_as_int(v), __ATOMIC_RELAXED,
                     __HIP_MEMORY_SCOPE_AGENT);
}
__device__ __forceinline__ float4 cload4(const float* a) {
  float4 r;
  r.x = cload(a + 0); r.y = cload(a + 1);
  r.z = cload(a + 2); r.w = cload(a + 3);
  return r;
}

__device__ __forceinline__ float wred(float v) {
#pragma unroll
  for (int m = 32; m; m >>= 1) v += __shfl_xor(v, m, 64);
  return v;
}

__device__ __forceinline__ float elu(float x) { return x > 0.f ? x : expm1f(x); }

__device__ __forceinline__ float dot4(float4 a, float4 b) {
  return a.x*b.x + a.y*b.y + a.z*b.z + a.w*b.w;
}

// grid barrier: NO fences. __syncthreads() drains each wave's vmcnt (sc1
// stores then ack'd at the coherence point); tid0 publishes per-WG flag;
// wave 0 polls all 64 flags in parallel with sc1 loads.
__device__ __forceinline__ void gridbar(int* flags, int phase) {
  __syncthreads();
  if (threadIdx.x == 0) {
    __hip_atomic_store(&flags[blockIdx.x * 16], phase,
                       __ATOMIC_RELAXED, __HIP_MEMORY_SCOPE_AGENT);
  }
  if (threadIdx.x < NWG) {
    while (__hip_atomic_load(&flags[threadIdx.x * 16],
                             __ATOMIC_RELAXED, __HIP_MEMORY_SCOPE_AGENT) < phase)
      __builtin_amdgcn_s_sleep(1);
  }
  __syncthreads();
}

__global__ __launch_bounds__(BLOCK, 1) void mvae_main(P p, int* flags) {
  const int tid  = threadIdx.x;
  const int lane = tid & 63;
  const int wvin = tid >> 6;                 // wave within WG, 0..3
  const int wv   = blockIdx.x * 4 + wvin;    // 0..255

  __shared__ float s_ml[64];   // mu[0..31], lv[32..63] (per-WG redundant)
  __shared__ float s_z[32];

  // ---- S0: enc0 row wv, x = [prev|curr] (124) ----
  {
    float4 w0 = make_float4(0.f,0.f,0.f,0.f);
    float4 x0 = make_float4(0.f,0.f,0.f,0.f);
    if (lane < 31) {
      w0 = *(const float4*)(p.ew0 + wv * 124 + 4 * lane);
      int i0 = 4 * lane;
      x0.x = (i0 + 0 < 62) ? p.prev[i0 + 0] : p.curr[i0 + 0 - 62];
      x0.y = (i0 + 1 < 62) ? p.prev[i0 + 1] : p.curr[i0 + 1 - 62];
      x0.z = (i0 + 2 < 62) ? p.prev[i0 + 2] : p.curr[i0 + 2 - 62];
      x0.w = (i0 + 3 < 62) ? p.prev[i0 + 3] : p.curr[i0 + 3 - 62];
    }
    float s = wred(dot4(w0, x0));
    if (!lane) cstore(&g_a0[wv], elu(s + p.eb0[wv]));
  }
  gridbar(flags, 1);

  // ---- S1: enc1 ----
  {
    float4 x = cload4(g_a0 + 4 * lane);
    float4 w = *(const float4*)(p.ew1 + wv * 256 + 4 * lane);
    float s = wred(dot4(w, x));
    if (!lane) cstore(&g_a1[wv], elu(s + p.eb1[wv]));
  }
  gridbar(flags, 2);

  // ---- S2: enc2 ----
  {
    float4 x = cload4(g_a1 + 4 * lane);
    float4 w = *(const float4*)(p.ew2 + wv * 256 + 4 * lane);
    float s = wred(dot4(w, x));
    if (!lane) cstore(&g_a2[wv], elu(s + p.eb2[wv]));
  }
  gridbar(flags, 3);

  // ---- S3 (LOCAL, no grid barrier): every WG computes mu/lv/z itself ----
  {
    float4 x = cload4(g_a2 + 4 * lane);
#pragma unroll
    for (int k = 0; k < 16; ++k) {
      int row = wvin * 16 + k;               // 0..63: mu rows then lv rows
      const float* wr = (row < 32) ? (p.muw + row * 256)
                                   : (p.lvw + (row - 32) * 256);
      float4 w = *(const float4*)(wr + 4 * lane);
      float s = wred(dot4(w, x));
      if (!lane)
        s_ml[row] = s + ((row < 32) ? p.mub[row] : p.lvb[row - 32]);
    }
    __syncthreads();
    if (tid < 32) {
      float mu = s_ml[tid], lv = s_ml[32 + tid];
      s_z[tid] = mu + p.eps[tid] * expf(0.5f * lv);
      if (blockIdx.x == 0) { p.out[62 + tid] = mu; p.out[94 + tid] = lv; }
    }
    __syncthreads();
  }

  // ---- S4: L0 — gate0 (256 rows) + expert h0 (1536 rows), x=[z|prev] (94) ----
  {
    float xa = (lane < 32) ? s_z[lane] : p.prev[lane - 32];
    float xb = (lane < 30) ? p.prev[32 + lane] : 0.f;
#pragma unroll
    for (int k = 0; k < 7; ++k) {
      const float* wr; float b; float* dst;
      if (k == 0) { wr = p.gw0 + wv * 94; b = p.gb0[wv]; dst = &g_g0[wv]; }
      else { int q = wv + 256 * (k - 1);
             wr = p.xw0 + q * 94; b = p.xb0[q]; dst = &g_h0[q]; }
      float wb = (lane < 30) ? wr[64 + lane] : 0.f;
      float s = wred(wr[lane] * xa + wb * xb);
      if (!lane) cstore(dst, elu(s + b));
    }
  }
  gridbar(flags, 4);

  // ---- S5: L1 — gate1 + expert h1 ----
  {
#pragma unroll
    for (int k = 0; k < 7; ++k) {
      if (k == 0) {
        float4 x = cload4(g_g0 + 4 * lane);
        float4 w = *(const float4*)(p.gw1 + wv * 256 + 4 * lane);
        float s = wred(dot4(w, x));
        if (!lane) cstore(&g_g1[wv], elu(s + p.gb1[wv]));
      } else {
        int q = wv + 256 * (k - 1);
        const float* wr = p.xw1 + q * 288;
        const float* h  = g_h0 + (k - 1) * 256;
        float4 w = *(const float4*)(wr + 4 * lane);
        float4 xh;
        if (lane < 8) xh = *(const float4*)(s_z + 4 * lane);
        else          xh = cload4(h + 4 * lane - 32);
        float s = dot4(w, xh);
        if (lane < 32) s += wr[256 + lane] * cload(h + 224 + lane);
        s = wred(s);
        if (!lane) cstore(&g_h1[q], elu(s + p.xb1[q]));
      }
    }
  }
  gridbar(flags, 5);

  // ---- S6: L2 — gate2 + expert h2 ----
  {
#pragma unroll
    for (int k = 0; k < 7; ++k) {
      if (k == 0) {
        float4 x = cload4(g_g1 + 4 * lane);
        float4 w = *(const float4*)(p.gw2 + wv * 256 + 4 * lane);
        float s = wred(dot4(w, x));
        if (!lane) cstore(&g_g2[wv], elu(s + p.gb2[wv]));
      } else {
        int q = wv + 256 * (k - 1);
        const float* wr = p.xw2 + q * 288;
        const float* h  = g_h1 + (k - 1) * 256;
        float4 w = *(const float4*)(wr + 4 * lane);
        float4 xh;
        if (lane < 8) xh = *(const float4*)(s_z + 4 * lane);
        else          xh = cload4(h + 4 * lane - 32);
        float s = dot4(w, xh);
        if (lane < 32) s += wr[256 + lane] * cload(h + 224 + lane);
        s = wred(s);
        if (!lane) cstore(&g_h2[q], elu(s + p.xb2[q]));
      }
    }
  }
  gridbar(flags, 6);

  // ---- S7: gate3 logits (6) + out_e (372) ----
  {
    if (wv < 6) {
      float4 x = cload4(g_g2 + 4 * lane);
      float4 w = *(const float4*)(p.gw3 + wv * 256 + 4 * lane);
      float s = wred(dot4(w, x));
      if (!lane) cstore(&g_gates[wv], s + p.gb3[wv]);   // raw logits
    } else {
      int q = wv - 6; int e = q / 62;
      const float* wr = p.xw3 + q * 288;
      const float* h  = g_h2 + e * 256;
      float4 w = *(const float4*)(wr + 4 * lane);
      float4 xh;
      if (lane < 8) xh = *(const float4*)(s_z + 4 * lane);
      else          xh = cload4(h + 4 * lane - 32);
      float s = dot4(w, xh);
      if (lane < 32) s += wr[256 + lane] * cload(h + 224 + lane);
      s = wred(s);
      if (!lane) cstore(&g_oute[q], s + p.xb3[q]);
    }
    if (wv < 122) {
      int q = wv + 250; int e = q / 62;
      const float* wr = p.xw3 + q * 288;
      const float* h  = g_h2 + e * 256;
      float4 w = *(const float4*)(wr + 4 * lane);
      float4 xh;
      if (lane < 8) xh = *(const float4*)(s_z + 4 * lane);
      else          xh = cload4(h + 4 * lane - 32);
      float s = dot4(w, xh);
      if (lane < 32) s += wr[256 + lane] * cload(h + 224 + lane);
      s = wred(s);
      if (!lane) cstore(&g_oute[q], s + p.xb3[q]);
    }
  }
  gridbar(flags, 7);

  // ---- S8: decoded = sum_e out_e * gates[e] ----
  if (blockIdx.x == 0 && tid < 62) {
    float s = 0.f;
#pragma unroll
    for (int e = 0; e < 6; ++e)
      s += cload(&g_oute[e * 62 + tid]) * cload(&g_gates[e]);
    p.out[tid] = s;
  }
}

extern "C" void kernel_launch(void* const* d_in, const int* in_sizes, int n_in,
                              void* d_out, int out_size, void* d_ws, size_t ws_size,
                              hipStream_t stream) {
  (void)in_sizes; (void)n_in; (void)out_size; (void)ws_size;
  const float* const* in = (const float* const*)d_in;
  P p;
  p.prev = in[0];  p.curr = in[1];  p.eps = in[2];
  p.ew0 = in[3];   p.eb0 = in[4];   p.ew1 = in[5];  p.eb1 = in[6];
  p.ew2 = in[7];   p.eb2 = in[8];
  p.muw = in[9];   p.mub = in[10];  p.lvw = in[11]; p.lvb = in[12];
  p.gw0 = in[13];  p.gb0 = in[14];  p.gw1 = in[15]; p.gb1 = in[16];
  p.gw2 = in[17];  p.gb2 = in[18];  p.gw3 = in[19]; p.gb3 = in[20];
  p.xw0 = in[21];  p.xb0 = in[22];  p.xw1 = in[23]; p.xb1 = in[24];
  p.xw2 = in[25];  p.xb2 = in[26];  p.xw3 = in[27]; p.xb3 = in[28];
  p.out = (float*)d_out;

  int* flags = (int*)d_ws;                       // 64 WGs x 16 ints (1 line each)
  hipMemsetAsync(flags, 0, NWG * 16 * sizeof(int), stream);
  mvae_main<<<NWG, BLOCK, 0, stream>>>(p, flags);
}

// Round 5
// 39.993 us; speedup vs baseline: 1.7613x; 1.2479x over previous
//
#include <hip/hip_runtime.h>
#include <math.h>

// MVAE forward, persistent kernel, round 5.
// - ALL weights a wave needs staged global->LDS via global_load_lds issued at
//   kernel entry (compiler can't sink it) -> 5.8MB streams at full MLP.
// - Activation vectors (g_a*, g_g*, g_h*) written with sc1 (MALL write-through)
//   and read via gll16 (cached path). Safe because L1/L2 are invalidated per
//   dispatch AND every g_* array is __align__(128): no cache line is ever
//   resident before its writer runs (round-4 bug was unaligned line sharing).
// - Scalars (mu/lv/gates/oute/flags) cross WGs via sc1 loads (proven path).

#define NWG   64
#define BLOCK 256

__device__ __align__(128) float g_a0[256];
__device__ __align__(128) float g_a1[256];
__device__ __align__(128) float g_a2[256];
__device__ __align__(128) float g_mu[32];
__device__ __align__(128) float g_lv[32];
__device__ __align__(128) float g_g0[256];
__device__ __align__(128) float g_g1[256];
__device__ __align__(128) float g_g2[256];
__device__ __align__(128) float g_gates[32];
__device__ __align__(128) float g_h0[1536];
__device__ __align__(128) float g_h1[1536];
__device__ __align__(128) float g_h2[1536];
__device__ __align__(128) float g_oute[384];

struct P {
  const float *prev, *curr, *eps;
  const float *ew0,*eb0,*ew1,*eb1,*ew2,*eb2;
  const float *muw,*mub,*lvw,*lvb;
  const float *gw0,*gb0,*gw1,*gb1,*gw2,*gb2,*gw3,*gb3;
  const float *xw0,*xb0,*xw1,*xb1,*xw2,*xb2,*xw3,*xb3;
  float* out;
};

__device__ __forceinline__ float cload(const float* a) {
  int v = __hip_atomic_load((const int*)a, __ATOMIC_RELAXED,
                            __HIP_MEMORY_SCOPE_AGENT);
  return __int_as_float(v);
}
__device__ __forceinline__ void cstore(float* a, float v) {
  __hip_atomic_store((int*)a, __float_as_int(v), __ATOMIC_RELAXED,
                     __HIP_MEMORY_SCOPE_AGENT);
}

__device__ __forceinline__ void gll16(const void* g, void* l) {
  __builtin_amdgcn_global_load_lds((const __attribute__((address_space(1))) void*)g,
                                   (__attribute__((address_space(3))) void*)l,
                                   16, 0, 0);
}
__device__ __forceinline__ void gll4(const void* g, void* l) {
  __builtin_amdgcn_global_load_lds((const __attribute__((address_space(1))) void*)g,
                                   (__attribute__((address_space(3))) void*)l,
                                   4, 0, 0);
}

__device__ __forceinline__ float wred(float v) {
#pragma unroll
  for (int m = 32; m; m >>= 1) v += __shfl_xor(v, m, 64);
  return v;
}
__device__ __forceinline__ float elu(float x) { return x > 0.f ? x : expm1f(x); }
__device__ __forceinline__ float dot4(float4 a, float4 b) {
  return a.x*b.x + a.y*b.y + a.z*b.z + a.w*b.w;
}

__device__ __forceinline__ void gridbar(int* flags, int phase) {
  __syncthreads();                 // vmcnt(0) drain: sc1 stores ack'd at MALL
  if (threadIdx.x == 0)
    __hip_atomic_store(&flags[blockIdx.x * 16], phase,
                       __ATOMIC_RELAXED, __HIP_MEMORY_SCOPE_AGENT);
  if (threadIdx.x < NWG) {
    while (__hip_atomic_load(&flags[threadIdx.x * 16],
                             __ATOMIC_RELAXED, __HIP_MEMORY_SCOPE_AGENT) < phase)
      __builtin_amdgcn_s_sleep(1);
  }
  __syncthreads();
}

// stage gate(256f)+expert(1536f) activations into LDS: 7 x 1KB wave-instrs
__device__ __forceinline__ void copy_act(const float* gg, const float* gh,
                                         float* sg, float* sh,
                                         int wvin, int lane) {
  if (wvin == 0) { gll16(gh +        lane*4, sh);
                   gll16(gh + 1024 + lane*4, sh + 1024); }
  if (wvin == 1) { gll16(gh +  256 + lane*4, sh +  256);
                   gll16(gh + 1280 + lane*4, sh + 1280); }
  if (wvin == 2) { gll16(gh +  512 + lane*4, sh +  512);
                   gll16(gg +        lane*4, sg); }
  if (wvin == 3) { gll16(gh +  768 + lane*4, sh +  768); }
}

__global__ __launch_bounds__(BLOCK, 1) void mvae_main(P p, int* flags) {
  const int tid  = threadIdx.x;
  const int lane = tid & 63;
  const int wvin = tid >> 6;                // 0..3
  const int W    = blockIdx.x * 4 + wvin;   // 0..255

  __shared__ __align__(16) float s_w1[4][256];      // enc1 rows
  __shared__ __align__(16) float s_w2[4][256];      // enc2 rows
  __shared__ __align__(16) float s_w3[4][256];      // mu/lv rows (WGs 0..15)
  __shared__ __align__(16) float s_w4[4][7][96];    // S4 rows (94f)
  __shared__ __align__(16) float s_w5[4][7][288];   // S5 rows
  __shared__ __align__(16) float s_w6[4][7][288];   // S6 rows
  __shared__ __align__(16) float s_w7[4][2][288];   // S7 rows
  __shared__ __align__(16) float s_g[256];
  __shared__ __align__(16) float s_h[1536];
  __shared__ __align__(16) float s_a[256];
  __shared__ float s_z[32];
  __shared__ float s_gg[8];
  __shared__ float s_o[384];

  // ---- early register loads (tiny, read-only) ----
  const float* w0r = p.ew0 + W * 124;
  float w0a = w0r[lane];
  float w0b = (lane < 60) ? w0r[64 + lane] : 0.f;
  float x0a = (lane < 62) ? p.prev[lane] : p.curr[lane - 62];
  float x0b = (lane < 60) ? p.curr[lane + 2] : 0.f;
  float prevA = (lane >= 32) ? p.prev[lane - 32] : 0.f;
  float prevB = (lane < 30) ? p.prev[32 + lane] : 0.f;
  float epsv  = (tid < 32) ? p.eps[tid] : 0.f;

  // ================= STAGING: all weights -> LDS (issued, not waited) =====
  gll16(p.ew1 + W * 256 + lane * 4, s_w1[wvin]);
  gll16(p.ew2 + W * 256 + lane * 4, s_w2[wvin]);
  if (blockIdx.x < 16) {
    const float* src = (W < 32) ? p.muw + W * 256 : p.lvw + (W - 32) * 256;
    gll16(src + lane * 4, s_w3[wvin]);
  }
#pragma unroll
  for (int k = 0; k < 7; ++k) {            // S4: rows W+256k, 94 floats
    int r = W + 256 * k;
    const float* src = (r < 256) ? p.gw0 + r * 94 : p.xw0 + (r - 256) * 94;
    float* dst = s_w4[wvin][k];
    if (lane < 23)       gll16(src + lane * 4, dst);
    else if (lane == 23) { gll4(src + 92, dst + 69);    // -> float 92
                           gll4(src + 93, dst + 70); }  // -> float 93
  }
#pragma unroll
  for (int k = 0; k < 7; ++k) {            // S5
    int r = W + 256 * k;
    float* dst = s_w5[wvin][k];
    if (r < 256) gll16(p.gw1 + r * 256 + lane * 4, dst);
    else {
      const float* src = p.xw1 + (r - 256) * 288;
      gll16(src + lane * 4, dst);
      if (lane < 8) gll16(src + 256 + lane * 4, dst + 256);
    }
  }
#pragma unroll
  for (int k = 0; k < 7; ++k) {            // S6
    int r = W + 256 * k;
    float* dst = s_w6[wvin][k];
    if (r < 256) gll16(p.gw2 + r * 256 + lane * 4, dst);
    else {
      const float* src = p.xw2 + (r - 256) * 288;
      gll16(src + lane * 4, dst);
      if (lane < 8) gll16(src + 256 + lane * 4, dst + 256);
    }
  }
  {                                        // S7 row A: W (always < 378)
    float* dst = s_w7[wvin][0];
    if (W < 6) gll16(p.gw3 + W * 256 + lane * 4, dst);
    else {
      const float* src = p.xw3 + (W - 6) * 288;
      gll16(src + lane * 4, dst);
      if (lane < 8) gll16(src + 256 + lane * 4, dst + 256);
    }
  }
  if (W < 122) {                           // S7 row B: W+256
    float* dst = s_w7[wvin][1];
    const float* src = p.xw3 + (W + 250) * 288;
    gll16(src + lane * 4, dst);
    if (lane < 8) gll16(src + 256 + lane * 4, dst + 256);
  }

  // ================= S0: enc0 =============================================
  {
    float s = wred(w0a * x0a + w0b * x0b);
    if (!lane) cstore(&g_a0[W], elu(s + p.eb0[W]));
  }
  gridbar(flags, 1);

  // ================= S1: enc1 =============================================
  if (wvin == 0) gll16((const float*)g_a0 + lane * 4, s_a);
  __syncthreads();
  {
    float4 w = *(const float4*)(s_w1[wvin] + 4 * lane);
    float4 x = *(const float4*)(s_a + 4 * lane);
    float s = wred(dot4(w, x));
    if (!lane) cstore(&g_a1[W], elu(s + p.eb1[W]));
  }
  gridbar(flags, 2);

  // ================= S2: enc2 =============================================
  if (wvin == 0) gll16((const float*)g_a1 + lane * 4, s_a);
  __syncthreads();
  {
    float4 w = *(const float4*)(s_w2[wvin] + 4 * lane);
    float4 x = *(const float4*)(s_a + 4 * lane);
    float s = wred(dot4(w, x));
    if (!lane) cstore(&g_a2[W], elu(s + p.eb2[W]));
  }
  gridbar(flags, 3);

  // ================= S3: mu / logvar (WGs 0..15) ==========================
  if (blockIdx.x < 16) {
    if (wvin == 0) gll16((const float*)g_a2 + lane * 4, s_a);
    __syncthreads();
    float4 w = *(const float4*)(s_w3[wvin] + 4 * lane);
    float4 x = *(const float4*)(s_a + 4 * lane);
    float s = wred(dot4(w, x));
    if (!lane) {
      if (W < 32) { float v = s + p.mub[W]; cstore(&g_mu[W], v); p.out[62 + W] = v; }
      else { int r = W - 32; float v = s + p.lvb[r]; cstore(&g_lv[r], v); p.out[94 + r] = v; }
    }
  }
  gridbar(flags, 4);

  // z into LDS (per WG, sc1 scalar reads)
  if (tid < 32)
    s_z[tid] = cload(&g_mu[tid]) + epsv * expf(0.5f * cload(&g_lv[tid]));
  __syncthreads();

  // ================= S4: gate0 + expert h0 (x=[z|prev], 94) ===============
  {
    float xa = (lane < 32) ? s_z[lane] : prevA;
#pragma unroll
    for (int k = 0; k < 7; ++k) {
      int r = W + 256 * k;
      const float* wrow = s_w4[wvin][k];
      float wb = (lane < 30) ? wrow[64 + lane] : 0.f;
      float s = wred(wrow[lane] * xa + wb * prevB);
      if (!lane) {
        if (r < 256) cstore(&g_g0[r], elu(s + p.gb0[r]));
        else         cstore(&g_h0[r - 256], elu(s + p.xb0[r - 256]));
      }
    }
  }
  gridbar(flags, 5);

  // ================= S5: gate1 + expert h1 ================================
  copy_act(g_g0, g_h0, s_g, s_h, wvin, lane);
  __syncthreads();
#pragma unroll
  for (int k = 0; k < 7; ++k) {
    int r = W + 256 * k;
    const float* wrow = s_w5[wvin][k];
    float4 w = *(const float4*)(wrow + 4 * lane);
    if (r < 256) {
      float4 x = *(const float4*)(s_g + 4 * lane);
      float s = wred(dot4(w, x));
      if (!lane) cstore(&g_g1[r], elu(s + p.gb1[r]));
    } else {
      int q = r - 256, e = q >> 8;
      float4 xh;
      if (lane < 8) xh = *(const float4*)(s_z + 4 * lane);
      else          xh = *(const float4*)(s_h + e * 256 + 4 * lane - 32);
      float s = dot4(w, xh);
      if (lane < 32) s += wrow[256 + lane] * s_h[e * 256 + 224 + lane];
      s = wred(s);
      if (!lane) cstore(&g_h1[q], elu(s + p.xb1[q]));
    }
  }
  gridbar(flags, 6);

  // ================= S6: gate2 + expert h2 ================================
  copy_act(g_g1, g_h1, s_g, s_h, wvin, lane);
  __syncthreads();
#pragma unroll
  for (int k = 0; k < 7; ++k) {
    int r = W + 256 * k;
    const float* wrow = s_w6[wvin][k];
    float4 w = *(const float4*)(wrow + 4 * lane);
    if (r < 256) {
      float4 x = *(const float4*)(s_g + 4 * lane);
      float s = wred(dot4(w, x));
      if (!lane) cstore(&g_g2[r], elu(s + p.gb2[r]));
    } else {
      int q = r - 256, e = q >> 8;
      float4 xh;
      if (lane < 8) xh = *(const float4*)(s_z + 4 * lane);
      else          xh = *(const float4*)(s_h + e * 256 + 4 * lane - 32);
      float s = dot4(w, xh);
      if (lane < 32) s += wrow[256 + lane] * s_h[e * 256 + 224 + lane];
      s = wred(s);
      if (!lane) cstore(&g_h2[q], elu(s + p.xb2[q]));
    }
  }
  gridbar(flags, 7);

  // ================= S7: gate3 logits + out_e =============================
  copy_act(g_g2, g_h2, s_g, s_h, wvin, lane);
  __syncthreads();
  {
    const float* wrow = s_w7[wvin][0];
    float4 w = *(const float4*)(wrow + 4 * lane);
    if (W < 6) {
      float4 x = *(const float4*)(s_g + 4 * lane);
      float s = wred(dot4(w, x));
      if (!lane) cstore(&g_gates[W], s + p.gb3[W]);    // raw logits
    } else {
      int q = W - 6, e = q / 62;
      float4 xh;
      if (lane < 8) xh = *(const float4*)(s_z + 4 * lane);
      else          xh = *(const float4*)(s_h + e * 256 + 4 * lane - 32);
      float s = dot4(w, xh);
      if (lane < 32) s += wrow[256 + lane] * s_h[e * 256 + 224 + lane];
      s = wred(s);
      if (!lane) cstore(&g_oute[q], s + p.xb3[q]);
    }
  }
  if (W < 122) {
    const float* wrow = s_w7[wvin][1];
    float4 w = *(const float4*)(wrow + 4 * lane);
    int q = W + 250, e = q / 62;
    float4 xh;
    if (lane < 8) xh = *(const float4*)(s_z + 4 * lane);
    else          xh = *(const float4*)(s_h + e * 256 + 4 * lane - 32);
    float s = dot4(w, xh);
    if (lane < 32) s += wrow[256 + lane] * s_h[e * 256 + 224 + lane];
    s = wred(s);
    if (!lane) cstore(&g_oute[q], s + p.xb3[q]);
  }
  gridbar(flags, 8);

  // ================= S8: decoded (WG0, parallel sc1 reads) ================
  if (blockIdx.x == 0) {
    s_o[tid] = cload(&g_oute[tid]);
    if (tid < 116) s_o[tid + 256] = cload(&g_oute[tid + 256]);
    if (tid < 6)   s_gg[tid] = cload(&g_gates[tid]);
    __syncthreads();
    if (tid < 62) {
      float s = 0.f;
#pragma unroll
      for (int e = 0; e < 6; ++e) s += s_o[e * 62 + tid] * s_gg[e];
      p.out[tid] = s;
    }
  }
}

extern "C" void kernel_launch(void* const* d_in, const int* in_sizes, int n_in,
                              void* d_out, int out_size, void* d_ws, size_t ws_size,
                              hipStream_t stream) {
  (void)in_sizes; (void)n_in; (void)out_size; (void)ws_size;
  const float* const* in = (const float* const*)d_in;
  P p;
  p.prev = in[0];  p.curr = in[1];  p.eps = in[2];
  p.ew0 = in[3];   p.eb0 = in[4];   p.ew1 = in[5];  p.eb1 = in[6];
  p.ew2 = in[7];   p.eb2 = in[8];
  p.muw = in[9];   p.mub = in[10];  p.lvw = in[11]; p.lvb = in[12];
  p.gw0 = in[13];  p.gb0 = in[14];  p.gw1 = in[15]; p.gb1 = in[16];
  p.gw2 = in[17];  p.gb2 = in[18];  p.gw3 = in[19]; p.gb3 = in[20];
  p.xw0 = in[21];  p.xb0 = in[22];  p.xw1 = in[23]; p.xb1 = in[24];
  p.xw2 = in[25];  p.xb2 = in[26];  p.xw3 = in[27]; p.xb3 = in[28];
  p.out = (float*)d_out;

  int* flags = (int*)d_ws;                        // 64 WGs x 1 cacheline
  hipMemsetAsync(flags, 0, NWG * 16 * sizeof(int), stream);
  mvae_main<<<NWG, BLOCK, 0, stream>>>(p, flags);
}